// Round 1
// baseline (526.588 us; speedup 1.0000x reference)
//
#include <hip/hip_runtime.h>
#include <hip/hip_bf16.h>

#define NN 8192
#define CH 256

typedef float f32x4 __attribute__((ext_vector_type(4)));
typedef __bf16 bf16x8 __attribute__((ext_vector_type(8)));

union FragU { uint4 u; bf16x8 h; };

static __device__ __forceinline__ unsigned short f2bf(float f) {
  union { float f; unsigned int u; } v; v.f = f;
  unsigned int x = v.u;
  return (unsigned short)((x + 0x7fffu + ((x >> 16) & 1u)) >> 16);  // RNE
}

#if defined(__has_builtin)
#if __has_builtin(__builtin_amdgcn_global_load_lds)
#define HAVE_GLL 1
#endif
#endif

#ifdef HAVE_GLL
// async 16B/lane global->LDS. LDS dest = wave-uniform base + lane*16 (linear).
static __device__ __forceinline__ void gload16(const void* g, void* l) {
  __builtin_amdgcn_global_load_lds(
      (const __attribute__((address_space(1))) void*)(unsigned long long)(g),
      (__attribute__((address_space(3))) void*)(unsigned int)(unsigned long long)(l),
      16, 0, 0);
}
#endif

static __device__ __forceinline__ unsigned int cvtpk(float a, float b) {
  unsigned int r;  // lo16 = bf16(a), hi16 = bf16(b), RNE
  asm("v_cvt_pk_bf16_f32 %0, %1, %2" : "=v"(r) : "v"(a), "v"(b));
  return r;
}

#define WAITV(n) asm volatile("s_waitcnt vmcnt(" #n ")" ::: "memory")
#define BARRIER() __builtin_amdgcn_s_barrier()

// ---------------- kernel 1: HT[j][k] = bf16(d[k]*H[k][j]), WT[j][c] = bf16(W[c][j])
__global__ __launch_bounds__(256) void k_prep(const float* __restrict__ Hm,
                                              const float* __restrict__ Dm,
                                              const float* __restrict__ Wm,
                                              unsigned short* __restrict__ HT,
                                              unsigned short* __restrict__ WT) {
  __shared__ float tile[64][65];
  int bx = blockIdx.x, t = threadIdx.x;
  bool isH = bx < 512;
  int b = isH ? bx : bx - 512;
  int r0 = (b >> 2) * 64;
  int j0 = (b & 3) * 64;
  const float* src = isH ? Hm : Wm;

  int r = t >> 2;
  int cq = (t & 3) * 16;
  float dval = isH ? rsqrtf(Dm[(size_t)(r0 + r) * (NN + 1)]) : 1.0f;
  const float* p = src + (size_t)(r0 + r) * CH + j0 + cq;
#pragma unroll
  for (int u = 0; u < 4; ++u) {
    float4 v = *(const float4*)(p + u * 4);
    tile[r][cq + u * 4 + 0] = v.x * dval;
    tile[r][cq + u * 4 + 1] = v.y * dval;
    tile[r][cq + u * 4 + 2] = v.z * dval;
    tile[r][cq + u * 4 + 3] = v.w * dval;
  }
  __syncthreads();
  int j = t >> 2;
  int kq = (t & 3) * 16;
  __align__(16) unsigned short ov[16];
#pragma unroll
  for (int i = 0; i < 16; ++i) ov[i] = f2bf(tile[kq + i][j]);
  unsigned short* dst = isH ? (HT + (size_t)(j0 + j) * NN + r0 + kq)
                            : (WT + (size_t)(j0 + j) * CH + r0 + kq);
  *(uint4*)dst = *(uint4*)ov;
  *(uint4*)(dst + 8) = *(uint4*)(ov + 8);
}

// ---------------- kernel 2: split-K GEMM  P[s][i][j] = sum_k bf16(A[i,k]) * HT[j,k]
// BM=128 x BN=256 tile, BK=64, 8 waves (2 row-groups x 4 col-groups).
// A staged fp32 via global_load_lds (16B) into XOR-swizzled double-buffered LDS;
// bf16 conversion at frag assembly (v_cvt_pk_bf16_f32). B frags straight from
// L2-resident HT. Raw s_barrier + counted vmcnt(12): one tile (4 stage + 8 B
// loads) always in flight across the barrier; drained to 0 only at the tail.
template <int SK>
__global__ __launch_bounds__(512, 2) void k_gemm1(const float* __restrict__ A,
                                                  const unsigned short* __restrict__ HT,
                                                  float* __restrict__ P) {
  constexpr int KC = NN / SK;    // K-chunk per block
  constexpr int NIT = KC / 64;   // BK=64 tiles (even)
  __shared__ float Asf[2][8192]; // [buf][128 rows][64 cols] fp32, 16B-window XOR swizzle
  const int bx = blockIdx.x;
  const int strip = bx / SK, s = bx % SK;
  const int i0 = strip * 128;
  const size_t kbase = (size_t)s * KC;
  const int t = threadIdx.x, l = t & 63, w = t >> 6;
  const int lan = l & 15, quad = l >> 4;
  const int wr = w >> 2, wc = w & 3;

  // Staging source: thread t, iter u covers LDS row = u*32 + (t>>4), window t&15.
  // Source column window pre-XOR'd with (row&7) so linear LDS writes land swizzled:
  // LDS[row][W] = A[row][W ^ (row&7)]  (16B windows). Reads apply the same XOR.
  const char* Ag = (const char*)A
      + ((size_t)(i0 + (t >> 4)) * NN + kbase) * 4
      + (size_t)((((t & 15) * 16) ^ (((t >> 4) & 7) * 16)));

  const unsigned short* Bb = HT + (size_t)(wc * 64 + lan) * NN + kbase + quad * 8;

  FragU b0[8], b1[8];
  f32x4 acc[4][4];
#pragma unroll
  for (int mt = 0; mt < 4; ++mt)
#pragma unroll
    for (int nt = 0; nt < 4; ++nt)
#pragma unroll
      for (int c = 0; c < 4; ++c) acc[mt][nt][c] = 0.0f;

  auto stage = [&](int kt, int buf) {
    const char* g = Ag + (size_t)kt * 256;
#ifdef HAVE_GLL
#pragma unroll
    for (int u = 0; u < 4; ++u)
      gload16(g + (size_t)u * ((size_t)32 * NN * 4), &Asf[buf][u * 2048 + w * 256]);
#else
    float4 tv[4];
#pragma unroll
    for (int u = 0; u < 4; ++u)
      tv[u] = *(const float4*)(g + (size_t)u * ((size_t)32 * NN * 4));
#pragma unroll
    for (int u = 0; u < 4; ++u)
      *(float4*)((char*)&Asf[buf][0] + (size_t)(u * 512 + t) * 16) = tv[u];
    asm volatile("s_waitcnt lgkmcnt(0)" ::: "memory");
#endif
  };

  auto loadB = [&](FragU (&dst)[8], int kt) {
    const unsigned short* p = Bb + (size_t)kt * 64;
#pragma unroll
    for (int ss = 0; ss < 2; ++ss)
#pragma unroll
      for (int nt = 0; nt < 4; ++nt)
        dst[ss * 4 + nt].u = *(const uint4*)(p + (size_t)nt * 16 * NN + ss * 32);
  };

  const int sw = (lan & 7) * 16;
  auto compute = [&](FragU (&b)[8], const char* Ab) {
#pragma unroll
    for (int ss = 0; ss < 2; ++ss) {
      FragU af[4];
#pragma unroll
      for (int mt = 0; mt < 4; ++mt) {
        const int row = wr * 64 + mt * 16 + lan;
        const char* rp = Ab + row * 256;
        const int x = ss * 128 + quad * 32;
        float4 va = *(const float4*)(rp + ((x) ^ sw));
        float4 vb = *(const float4*)(rp + ((x + 16) ^ sw));
        af[mt].u.x = cvtpk(va.x, va.y);
        af[mt].u.y = cvtpk(va.z, va.w);
        af[mt].u.z = cvtpk(vb.x, vb.y);
        af[mt].u.w = cvtpk(vb.z, vb.w);
      }
#pragma unroll
      for (int mt = 0; mt < 4; ++mt)
#pragma unroll
        for (int nt = 0; nt < 4; ++nt)
          acc[mt][nt] = __builtin_amdgcn_mfma_f32_16x16x32_bf16(af[mt].h, b[ss * 4 + nt].h,
                                                                acc[mt][nt], 0, 0, 0);
    }
  };

  stage(0, 0);
  loadB(b0, 0);
#pragma unroll 1
  for (int kt = 0; kt < NIT; kt += 2) {
    // even tile kt (buf0): issue kt+1, keep its 12 loads in flight
    stage(kt + 1, 1);
    loadB(b1, kt + 1);
    WAITV(12);       // tile kt's 4 stage + 8 B loads retired; 12 newest stay in flight
    BARRIER();       // all waves' stage(kt) portions visible
    compute(b0, (const char*)&Asf[0][0]);
    BARRIER();       // buf1... wait: protects buf0 from being overwritten below
    // odd tile kt+1 (buf1)
    if (kt + 2 < NIT) {
      stage(kt + 2, 0);
      loadB(b0, kt + 2);
      WAITV(12);
    } else {
      WAITV(0);
    }
    BARRIER();
    compute(b1, (const char*)&Asf[1][0]);
    BARRIER();
  }

  float* Pp = P + ((size_t)s * NN + i0) * CH;
#pragma unroll
  for (int mt = 0; mt < 4; ++mt)
#pragma unroll
    for (int nt = 0; nt < 4; ++nt)
#pragma unroll
      for (int r = 0; r < 4; ++r)
        Pp[(size_t)(wr * 64 + mt * 16 + quad * 4 + r) * CH + wc * 64 + nt * 16 + lan]
            = acc[mt][nt][r];
}

// ---------------- kernel 3: out[i][j] = sum_c ( d[i]*sum_s P[s][i][c] ) * WT[j][c]
// 512 blocks x 16 rows; G in LDS; W frags straight from L2-hot WT.
template <int SK>
__global__ __launch_bounds__(256) void k_gemm2(const float* __restrict__ P,
                                               const float* __restrict__ Dm,
                                               const unsigned short* __restrict__ WT,
                                               float* __restrict__ out) {
  __shared__ unsigned short Gs[16][264];
  const int bx = blockIdx.x, t = threadIdx.x, l = t & 63, w = t >> 6;
  const int lan = l & 15, quad = l >> 4;
  const int i0 = bx * 16;
  {
    const int r = t >> 4, c0 = (t & 15) * 16;
    float dval = rsqrtf(Dm[(size_t)(i0 + r) * (NN + 1)]);
    const float* pp = P + (size_t)(i0 + r) * CH + c0;
    __align__(16) unsigned short g[16];
#pragma unroll
    for (int u = 0; u < 4; ++u) {
      float sx = 0.f, sy = 0.f, sz = 0.f, sw2 = 0.f;
#pragma unroll
      for (int s = 0; s < SK; ++s) {
        float4 v = *(const float4*)(pp + (size_t)s * NN * CH + u * 4);
        sx += v.x; sy += v.y; sz += v.z; sw2 += v.w;
      }
      g[u * 4 + 0] = f2bf(sx * dval);
      g[u * 4 + 1] = f2bf(sy * dval);
      g[u * 4 + 2] = f2bf(sz * dval);
      g[u * 4 + 3] = f2bf(sw2 * dval);
    }
    *(uint4*)&Gs[r][c0] = *(uint4*)g;
    *(uint4*)&Gs[r][c0 + 8] = *(uint4*)(g + 8);
  }
  __syncthreads();
  const int j0 = w * 64;
  f32x4 acc[4];
#pragma unroll
  for (int nt = 0; nt < 4; ++nt)
#pragma unroll
    for (int c = 0; c < 4; ++c) acc[nt][c] = 0.0f;
#pragma unroll
  for (int ks = 0; ks < 8; ++ks) {
    FragU af;
    af.u = *(const uint4*)&Gs[lan][ks * 32 + quad * 8];
#pragma unroll
    for (int nt = 0; nt < 4; ++nt) {
      FragU bw;
      bw.u = *(const uint4*)&WT[(size_t)(j0 + nt * 16 + lan) * CH + ks * 32 + quad * 8];
      acc[nt] = __builtin_amdgcn_mfma_f32_16x16x32_bf16(af.h, bw.h, acc[nt], 0, 0, 0);
    }
  }
#pragma unroll
  for (int nt = 0; nt < 4; ++nt)
#pragma unroll
    for (int r = 0; r < 4; ++r)
      out[(size_t)(i0 + quad * 4 + r) * CH + j0 + nt * 16 + lan] = acc[nt][r];
}

extern "C" void kernel_launch(void* const* d_in, const int* in_sizes, int n_in,
                              void* d_out, int out_size, void* d_ws, size_t ws_size,
                              hipStream_t stream) {
  const float* A  = (const float*)d_in[0];
  const float* Dm = (const float*)d_in[1];
  const float* Hm = (const float*)d_in[2];
  const float* Wm = (const float*)d_in[3];
  float* out = (float*)d_out;
  char* ws = (char*)d_ws;
  unsigned short* HT = (unsigned short*)ws;                       // 4 MiB
  unsigned short* WT = (unsigned short*)(ws + (size_t)4194304);   // 128 KiB
  float* P = (float*)(ws + (size_t)4194304 + 131072);             // SK * 8 MiB

  const size_t base = 4194304 + 131072;
  const size_t needS4 = base + (size_t)4 * NN * CH * 4;           // ~36.2 MiB

  hipLaunchKernelGGL(k_prep, dim3(528), dim3(256), 0, stream, Hm, Dm, Wm, HT, WT);
  if (ws_size >= needS4) {
    hipLaunchKernelGGL((k_gemm1<4>), dim3(256), dim3(512), 0, stream, A, HT, P);
    hipLaunchKernelGGL((k_gemm2<4>), dim3(512), dim3(256), 0, stream, P, Dm, WT, out);
  } else {
    hipLaunchKernelGGL((k_gemm1<2>), dim3(128), dim3(512), 0, stream, A, HT, P);
    hipLaunchKernelGGL((k_gemm2<2>), dim3(512), dim3(256), 0, stream, P, Dm, WT, out);
  }
}

// Round 2
// 522.705 us; speedup vs baseline: 1.0074x; 1.0074x over previous
//
#include <hip/hip_runtime.h>
#include <hip/hip_bf16.h>

#define NN 8192
#define CH 256

typedef float f32x4 __attribute__((ext_vector_type(4)));
typedef __bf16 bf16x8 __attribute__((ext_vector_type(8)));

union FragU { uint4 u; bf16x8 h; };

static __device__ __forceinline__ unsigned short f2bf(float f) {
  union { float f; unsigned int u; } v; v.f = f;
  unsigned int x = v.u;
  return (unsigned short)((x + 0x7fffu + ((x >> 16) & 1u)) >> 16);  // RNE
}

#if defined(__has_builtin)
#if __has_builtin(__builtin_amdgcn_global_load_lds)
#define HAVE_GLL 1
#endif
#endif

#ifdef HAVE_GLL
// async 16B/lane global->LDS. LDS dest = wave-uniform base + lane*16 (linear).
static __device__ __forceinline__ void gload16(const void* g, void* l) {
  __builtin_amdgcn_global_load_lds(
      (const __attribute__((address_space(1))) void*)(unsigned long long)(g),
      (__attribute__((address_space(3))) void*)(unsigned int)(unsigned long long)(l),
      16, 0, 0);
}
#endif

static __device__ __forceinline__ unsigned int cvtpk(float a, float b) {
  unsigned int r;  // lo16 = bf16(a), hi16 = bf16(b), RNE
  asm("v_cvt_pk_bf16_f32 %0, %1, %2" : "=v"(r) : "v"(a), "v"(b));
  return r;
}

#define WAITV(n) asm volatile("s_waitcnt vmcnt(" #n ")" ::: "memory")
#define BARRIER() __builtin_amdgcn_s_barrier()

// ---------------- kernel 1: HT[j][k] = bf16(d[k]*H[k][j]), WT[j][c] = bf16(W[c][j])
__global__ __launch_bounds__(256) void k_prep(const float* __restrict__ Hm,
                                              const float* __restrict__ Dm,
                                              const float* __restrict__ Wm,
                                              unsigned short* __restrict__ HT,
                                              unsigned short* __restrict__ WT) {
  __shared__ float tile[64][65];
  int bx = blockIdx.x, t = threadIdx.x;
  bool isH = bx < 512;
  int b = isH ? bx : bx - 512;
  int r0 = (b >> 2) * 64;
  int j0 = (b & 3) * 64;
  const float* src = isH ? Hm : Wm;

  int r = t >> 2;
  int cq = (t & 3) * 16;
  float dval = isH ? rsqrtf(Dm[(size_t)(r0 + r) * (NN + 1)]) : 1.0f;
  const float* p = src + (size_t)(r0 + r) * CH + j0 + cq;
#pragma unroll
  for (int u = 0; u < 4; ++u) {
    float4 v = *(const float4*)(p + u * 4);
    tile[r][cq + u * 4 + 0] = v.x * dval;
    tile[r][cq + u * 4 + 1] = v.y * dval;
    tile[r][cq + u * 4 + 2] = v.z * dval;
    tile[r][cq + u * 4 + 3] = v.w * dval;
  }
  __syncthreads();
  int j = t >> 2;
  int kq = (t & 3) * 16;
  __align__(16) unsigned short ov[16];
#pragma unroll
  for (int i = 0; i < 16; ++i) ov[i] = f2bf(tile[kq + i][j]);
  unsigned short* dst = isH ? (HT + (size_t)(j0 + j) * NN + r0 + kq)
                            : (WT + (size_t)(j0 + j) * CH + r0 + kq);
  *(uint4*)dst = *(uint4*)ov;
  *(uint4*)(dst + 8) = *(uint4*)(ov + 8);
}

// ---------------- kernel 2: split-K GEMM  P[s][i][j] = sum_k bf16(A[i,k]) * HT[j,k]
// BM=128 x BN=256 tile, BK=64, 8 waves (2 row-groups x 4 col-groups).
// A staged fp32 via global_load_lds (16B) into XOR-swizzled double-buffered LDS;
// bf16 conversion at frag assembly (v_cvt_pk_bf16_f32). B frags straight from
// L2-resident HT. Raw s_barrier + counted vmcnt(12): one tile (4 stage + 8 B
// loads) always in flight across the barrier; drained to 0 only at the tail.
//
// launch_bounds(512, 1): grid is 1 block/CU anyway; demanding 2 blocks/CU
// capped VGPR at 128 vs ~180 live state -> hot-loop scratch spills (round 1).
template <int SK>
__global__ __launch_bounds__(512, 1) void k_gemm1(const float* __restrict__ A,
                                                  const unsigned short* __restrict__ HT,
                                                  float* __restrict__ P) {
  constexpr int KC = NN / SK;    // K-chunk per block
  constexpr int NIT = KC / 64;   // BK=64 tiles (even)
  __shared__ float Asf[2][8192]; // [buf][128 rows][64 cols] fp32, 16B-window XOR swizzle
  const int bx = blockIdx.x;
  const int strip = bx / SK, s = bx % SK;
  const int i0 = strip * 128;
  const size_t kbase = (size_t)s * KC;
  const int t = threadIdx.x, l = t & 63, w = t >> 6;
  const int lan = l & 15, quad = l >> 4;
  const int wr = w >> 2, wc = w & 3;

  // Staging source: thread t, iter u covers LDS row = u*32 + (t>>4), window t&15.
  // Source column window pre-XOR'd with (row&7) so linear LDS writes land swizzled:
  // LDS[row][W] = A[row][W ^ (row&7)]  (16B windows). Reads apply the same XOR.
  const char* Ag = (const char*)A
      + ((size_t)(i0 + (t >> 4)) * NN + kbase) * 4
      + (size_t)((((t & 15) * 16) ^ (((t >> 4) & 7) * 16)));

  const unsigned short* Bb = HT + (size_t)(wc * 64 + lan) * NN + kbase + quad * 8;

  FragU b0[8], b1[8];
  f32x4 acc[4][4];
#pragma unroll
  for (int mt = 0; mt < 4; ++mt)
#pragma unroll
    for (int nt = 0; nt < 4; ++nt)
#pragma unroll
      for (int c = 0; c < 4; ++c) acc[mt][nt][c] = 0.0f;

  auto stage = [&](int kt, int buf) {
    const char* g = Ag + (size_t)kt * 256;
#ifdef HAVE_GLL
#pragma unroll
    for (int u = 0; u < 4; ++u)
      gload16(g + (size_t)u * ((size_t)32 * NN * 4), &Asf[buf][u * 2048 + w * 256]);
#else
    float4 tv[4];
#pragma unroll
    for (int u = 0; u < 4; ++u)
      tv[u] = *(const float4*)(g + (size_t)u * ((size_t)32 * NN * 4));
#pragma unroll
    for (int u = 0; u < 4; ++u)
      *(float4*)((char*)&Asf[buf][0] + (size_t)(u * 512 + t) * 16) = tv[u];
    asm volatile("s_waitcnt lgkmcnt(0)" ::: "memory");
#endif
  };

  auto loadB = [&](FragU (&dst)[8], int kt) {
    const unsigned short* p = Bb + (size_t)kt * 64;
#pragma unroll
    for (int ss = 0; ss < 2; ++ss)
#pragma unroll
      for (int nt = 0; nt < 4; ++nt)
        dst[ss * 4 + nt].u = *(const uint4*)(p + (size_t)nt * 16 * NN + ss * 32);
  };

  const int sw = (lan & 7) * 16;
  auto compute = [&](FragU (&b)[8], const char* Ab) {
#pragma unroll
    for (int ss = 0; ss < 2; ++ss) {
      FragU af[4];
#pragma unroll
      for (int mt = 0; mt < 4; ++mt) {
        const int row = wr * 64 + mt * 16 + lan;
        const char* rp = Ab + row * 256;
        const int x = ss * 128 + quad * 32;
        float4 va = *(const float4*)(rp + ((x) ^ sw));
        float4 vb = *(const float4*)(rp + ((x + 16) ^ sw));
        af[mt].u.x = cvtpk(va.x, va.y);
        af[mt].u.y = cvtpk(va.z, va.w);
        af[mt].u.z = cvtpk(vb.x, vb.y);
        af[mt].u.w = cvtpk(vb.z, vb.w);
      }
#pragma unroll
      for (int mt = 0; mt < 4; ++mt)
#pragma unroll
        for (int nt = 0; nt < 4; ++nt)
          acc[mt][nt] = __builtin_amdgcn_mfma_f32_16x16x32_bf16(af[mt].h, b[ss * 4 + nt].h,
                                                                acc[mt][nt], 0, 0, 0);
    }
  };

  stage(0, 0);
  loadB(b0, 0);
#pragma unroll 1
  for (int kt = 0; kt < NIT; kt += 2) {
    // even tile kt (buf0): issue kt+1, keep its 12 loads in flight
    stage(kt + 1, 1);
    loadB(b1, kt + 1);
    WAITV(12);       // tile kt's 4 stage + 8 B loads retired; 12 newest stay in flight
    BARRIER();       // all waves' stage(kt) portions visible
    compute(b0, (const char*)&Asf[0][0]);
    BARRIER();       // protects buf0 from being overwritten below
    // odd tile kt+1 (buf1)
    if (kt + 2 < NIT) {
      stage(kt + 2, 0);
      loadB(b0, kt + 2);
      WAITV(12);
    } else {
      WAITV(0);
    }
    BARRIER();
    compute(b1, (const char*)&Asf[1][0]);
    BARRIER();
  }

  float* Pp = P + ((size_t)s * NN + i0) * CH;
#pragma unroll
  for (int mt = 0; mt < 4; ++mt)
#pragma unroll
    for (int nt = 0; nt < 4; ++nt)
#pragma unroll
      for (int r = 0; r < 4; ++r)
        Pp[(size_t)(wr * 64 + mt * 16 + quad * 4 + r) * CH + wc * 64 + nt * 16 + lan]
            = acc[mt][nt][r];
}

// ---------------- kernel 3: out[i][j] = sum_c ( d[i]*sum_s P[s][i][c] ) * WT[j][c]
// 512 blocks x 16 rows; G in LDS; W frags straight from L2-hot WT.
template <int SK>
__global__ __launch_bounds__(256) void k_gemm2(const float* __restrict__ P,
                                               const float* __restrict__ Dm,
                                               const unsigned short* __restrict__ WT,
                                               float* __restrict__ out) {
  __shared__ unsigned short Gs[16][264];
  const int bx = blockIdx.x, t = threadIdx.x, l = t & 63, w = t >> 6;
  const int lan = l & 15, quad = l >> 4;
  const int i0 = bx * 16;
  {
    const int r = t >> 4, c0 = (t & 15) * 16;
    float dval = rsqrtf(Dm[(size_t)(i0 + r) * (NN + 1)]);
    const float* pp = P + (size_t)(i0 + r) * CH + c0;
    __align__(16) unsigned short g[16];
#pragma unroll
    for (int u = 0; u < 4; ++u) {
      float sx = 0.f, sy = 0.f, sz = 0.f, sw2 = 0.f;
#pragma unroll
      for (int s = 0; s < SK; ++s) {
        float4 v = *(const float4*)(pp + (size_t)s * NN * CH + u * 4);
        sx += v.x; sy += v.y; sz += v.z; sw2 += v.w;
      }
      g[u * 4 + 0] = f2bf(sx * dval);
      g[u * 4 + 1] = f2bf(sy * dval);
      g[u * 4 + 2] = f2bf(sz * dval);
      g[u * 4 + 3] = f2bf(sw2 * dval);
    }
    *(uint4*)&Gs[r][c0] = *(uint4*)g;
    *(uint4*)&Gs[r][c0 + 8] = *(uint4*)(g + 8);
  }
  __syncthreads();
  const int j0 = w * 64;
  f32x4 acc[4];
#pragma unroll
  for (int nt = 0; nt < 4; ++nt)
#pragma unroll
    for (int c = 0; c < 4; ++c) acc[nt][c] = 0.0f;
#pragma unroll
  for (int ks = 0; ks < 8; ++ks) {
    FragU af;
    af.u = *(const uint4*)&Gs[lan][ks * 32 + quad * 8];
#pragma unroll
    for (int nt = 0; nt < 4; ++nt) {
      FragU bw;
      bw.u = *(const uint4*)&WT[(size_t)(j0 + nt * 16 + lan) * CH + ks * 32 + quad * 8];
      acc[nt] = __builtin_amdgcn_mfma_f32_16x16x32_bf16(af.h, bw.h, acc[nt], 0, 0, 0);
    }
  }
#pragma unroll
  for (int nt = 0; nt < 4; ++nt)
#pragma unroll
    for (int r = 0; r < 4; ++r)
      out[(size_t)(i0 + quad * 4 + r) * CH + j0 + nt * 16 + lan] = acc[nt][r];
}

extern "C" void kernel_launch(void* const* d_in, const int* in_sizes, int n_in,
                              void* d_out, int out_size, void* d_ws, size_t ws_size,
                              hipStream_t stream) {
  const float* A  = (const float*)d_in[0];
  const float* Dm = (const float*)d_in[1];
  const float* Hm = (const float*)d_in[2];
  const float* Wm = (const float*)d_in[3];
  float* out = (float*)d_out;
  char* ws = (char*)d_ws;
  unsigned short* HT = (unsigned short*)ws;                       // 4 MiB
  unsigned short* WT = (unsigned short*)(ws + (size_t)4194304);   // 128 KiB
  float* P = (float*)(ws + (size_t)4194304 + 131072);             // SK * 8 MiB

  const size_t base = 4194304 + 131072;
  const size_t needS4 = base + (size_t)4 * NN * CH * 4;           // ~36.2 MiB

  hipLaunchKernelGGL(k_prep, dim3(528), dim3(256), 0, stream, Hm, Dm, Wm, HT, WT);
  if (ws_size >= needS4) {
    hipLaunchKernelGGL((k_gemm1<4>), dim3(256), dim3(512), 0, stream, A, HT, P);
    hipLaunchKernelGGL((k_gemm2<4>), dim3(512), dim3(256), 0, stream, P, Dm, WT, out);
  } else {
    hipLaunchKernelGGL((k_gemm1<2>), dim3(128), dim3(512), 0, stream, A, HT, P);
    hipLaunchKernelGGL((k_gemm2<2>), dim3(512), dim3(256), 0, stream, P, Dm, WT, out);
  }
}